// Round 6
// baseline (119.608 us; speedup 1.0000x reference)
//
#include <hip/hip_runtime.h>
#include <cmath>

// Static problem config (matches reference)
#define RB 20
#define RA 19
#define NPT (RB*RA)
#define DZ 25
#define DIN 9
#define MULT 128
#define CH 128

// ---------------------------------------------------------------------------
// Real-Gaunt selection rules (exact superset of nonzeros; verified R3/R4:
// same absmax as dense). 162 of 2025 (d1,d2,dz) entries survive.
__host__ __device__ constexpr int L_of(int d) { return d == 0 ? 0 : d < 4 ? 1 : d < 9 ? 2 : d < 16 ? 3 : 4; }
__host__ __device__ constexpr int M_of(int d) { return d - L_of(d) * L_of(d) - L_of(d); }
__host__ __device__ constexpr bool gz_nz(int d1, int d2, int dz) {
    const int l1 = L_of(d1), l2 = L_of(d2), l3 = L_of(dz);
    const int m1 = M_of(d1), m2 = M_of(d2), m3 = M_of(dz);
    const int lo = l1 > l2 ? l1 - l2 : l2 - l1;
    if (l3 < lo || l3 > l1 + l2) return false;
    if ((l1 + l2 + l3) & 1) return false;
    const int a1 = m1 < 0 ? -m1 : m1, a2 = m2 < 0 ? -m2 : m2, a3 = m3 < 0 ? -m3 : m3;
    const int sum = a1 + a2, dif = a1 > a2 ? a1 - a2 : a2 - a1;
    if (a3 != sum && a3 != dif) return false;
    if (((m1 < 0) + (m2 < 0) + (m3 < 0)) & 1) return false;
    return true;
}
__host__ __device__ constexpr bool pair_any(int d1, int d2) {
    for (int dz = 0; dz < DZ; ++dz) if (gz_nz(d1, d2, dz)) return true;
    return false;
}

// ---------------------------------------------------------------------------
// Host: transposed dense real-Gaunt table Gt[d1*9+d2][28] in fp64 from the
// reference's own quadrature. Cols 25..27 zero pads. Rule-zero entries
// (~1e-16 quadrature noise) forced to exactly 0.0f.
static void host_build_gaunt(float* out /* 81*28, zero-padded */) {
    const double PI = 3.14159265358979323846;
    double xq[RB], wq[RB];
    for (int i = 0; i < RB; ++i) {
        double x = cos(PI * (i + 0.75) / (RB + 0.5));
        double dp = 0.0;
        for (int it = 0; it < 100; ++it) {
            double p0 = 1.0, p1 = x;
            for (int k = 2; k <= RB; ++k) {
                double p2 = ((2.0*k - 1.0)*x*p1 - (k - 1.0)*p0) / (double)k;
                p0 = p1; p1 = p2;
            }
            dp = RB * (x*p1 - p0) / (x*x - 1.0);
            double dx = p1 / dp;
            x -= dx;
            if (fabs(dx) < 1e-15) break;
        }
        {
            double p0 = 1.0, p1 = x;
            for (int k = 2; k <= RB; ++k) {
                double p2 = ((2.0*k - 1.0)*x*p1 - (k - 1.0)*p0) / (double)k;
                p0 = p1; p1 = p2;
            }
            dp = RB * (x*p1 - p0) / (x*x - 1.0);
        }
        xq[i] = x;
        wq[i] = 2.0 / ((1.0 - x*x)*dp*dp);
    }
    static double Y[DZ][NPT];
    static double qws[NPT];
    for (int b = 0; b < RB; ++b) {
        double ct = xq[b], st = sqrt(fmax(0.0, 1.0 - ct*ct));
        double P[5][5]; double pmm = 1.0;
        for (int m = 0; m <= 4; ++m) {
            if (m > 0) pmm *= -(2.0*m - 1.0) * st;
            P[m][m] = pmm;
            if (m < 4) {
                double pp = pmm, pc = ct*(2.0*m + 1.0)*pmm;
                P[m+1][m] = pc;
                for (int l = m + 2; l <= 4; ++l) {
                    double pn = ((2.0*l - 1.0)*ct*pc - (double)(l + m - 1)*pp) / (double)(l - m);
                    P[l][m] = pn; pp = pc; pc = pn;
                }
            }
        }
        for (int a = 0; a < RA; ++a) {
            int pt = b*RA + a;
            qws[pt] = wq[b] * (2.0*PI/(double)RA);
            double alpha = 2.0*PI*(double)a/(double)RA;
            for (int l = 0; l <= 4; ++l)
                for (int m = -l; m <= l; ++m) {
                    int am = m < 0 ? -m : m;
                    double fr = 1.0;
                    for (int i = l - am + 1; i <= l + am; ++i) fr *= (double)i;
                    double nlm = sqrt((2.0*l + 1.0) / (4.0*PI) / fr);
                    double ang = (m == 0) ? 1.0
                               : (m > 0 ? sqrt(2.0)*cos(am*alpha) : sqrt(2.0)*sin(am*alpha));
                    Y[l*l + l + m][pt] = nlm * P[l][am] * ang;
                }
        }
    }
    for (int pr = 0; pr < 81; ++pr) {
        int d1 = pr / 9, d2 = pr % 9;
        for (int d = 0; d < DZ; ++d) {
            double s = 0.0;
            for (int p = 0; p < NPT; ++p)
                s += Y[d][p] * Y[d1][p] * Y[d2][p] * qws[p];
            out[pr*28 + d] = gz_nz(d1, d2, d) ? (float)s : 0.0f;
        }
    }
}

// ---------------------------------------------------------------------------
// Sparse stage C, single node, full dz range. Same (d1 asc, d2 asc, dz asc)
// order among nonzero terms as the dense loop -> bit-identical.
template<int D1, int D2, int DZi>
__device__ __forceinline__ void c_dz(const float* __restrict__ g, float p, float* a) {
    if constexpr (DZi < DZ) {
        if constexpr (gz_nz(D1, D2, DZi))
            a[DZi] = fmaf(p, g[(D1 * 9 + D2) * 28 + DZi], a[DZi]);   // b32 bcast
        c_dz<D1, D2, DZi + 1>(g, p, a);
    }
}
template<int D1, int D2>
__device__ __forceinline__ void c_d2(const float* __restrict__ g,
                                     const float* xr, const float* yr, float* a) {
    if constexpr (D2 < 9) {
        if constexpr (pair_any(D1, D2))
            c_dz<D1, D2, 0>(g, xr[D1] * yr[D2], a);
        c_d2<D1, D2 + 1>(g, xr, yr, a);
    }
}
template<int D1>
__device__ __forceinline__ void c_d1(const float* __restrict__ g,
                                     const float* xr, const float* yr, float* a) {
    if constexpr (D1 < 9) {
        c_d2<D1, 0>(g, xr, yr, a);
        c_d1<D1 + 1>(g, xr, yr, a);
    }
}

// ---------------------------------------------------------------------------
// Stage D: wave owns l-aligned d-range [D0,D0+ND) covering NL wz l-blocks
// starting at L0 (each wz element read once per block); lane owns e-pair
// (2*lane, 2*lane+1) -> float2 wz loads. Single node. Per-(e,d) accumulation
// order (c0 asc, k asc) identical to R0/R4 -> bit-exact.
template<int D0, int ND, int L0, int NL>
__device__ __forceinline__ void d_tile(const float* sZ, const float* __restrict__ wz,
                                       float* __restrict__ po, int lane) {
    const float s128 = 0.08838834764831845f;
    const int e2 = lane << 1;
    float acc[ND * 2];
    #pragma unroll
    for (int i = 0; i < ND * 2; ++i) acc[i] = 0.f;
    for (int c0 = 0; c0 < CH; c0 += 4) {
        float2 w[NL * 4];
        #pragma unroll
        for (int j = 0; j < NL; ++j)
            #pragma unroll
            for (int k = 0; k < 4; ++k)
                w[j * 4 + k] = *(const float2*)(wz + (L0 + j) * 16384 + (c0 + k) * 128 + e2);
        #pragma unroll
        for (int i = 0; i < ND; ++i) {
            const int d = D0 + i;
            const int l = (d == 0) ? 0 : (d < 4) ? 1 : (d < 9) ? 2 : (d < 16) ? 3 : 4;
            float4 z4 = *(const float4*)(sZ + d * 128 + c0);     // broadcast
            #pragma unroll
            for (int k = 0; k < 4; ++k) {
                float zc = (k == 0) ? z4.x : (k == 1) ? z4.y : (k == 2) ? z4.z : z4.w;
                acc[i*2+0] = fmaf(zc, w[(l - L0) * 4 + k].x, acc[i*2+0]);
                acc[i*2+1] = fmaf(zc, w[(l - L0) * 4 + k].y, acc[i*2+1]);
            }
        }
    }
    #pragma unroll
    for (int i = 0; i < ND; ++i) {
        po[e2 * 25 + D0 + i]       = acc[i*2+0] * s128;
        po[(e2 + 1) * 25 + D0 + i] = acc[i*2+1] * s128;
    }
}

// ---------------------------------------------------------------------------
// R6: ONE node per block, 128 threads (2 waves), grid = N = 1024.
// Rationale (R0-R5 evidence): duration is pinned at ~54us by stall time that
// scales with nothing instruction-level; 8 waves/CU are phase-locked by
// block-wide barriers. This version keeps per-thread instruction patterns
// EXACTLY as proven (same per-output fma orders -> bit-identical) but:
//  - 31 KB LDS (sZ aliases sXY) -> 5 blocks/CU capacity, 4 resident
//    = 16 waves/CU (2x TLP), barriers span only 2 waves,
//  - 4 independent blocks per CU stagger phases (D's VMEM overlaps B's LDS).
// Chip-wide VMEM instr count ~= R0 (c-pair/e-pair float2 mappings compensate
// the halved block size). Cost: weight L2 traffic doubles (~18 TB/s, under
// the 34.5 TB/s ceiling).
__global__ __launch_bounds__(128) void gaunt_fused(
    const float* __restrict__ xg, const float* __restrict__ yg,
    const float* __restrict__ wxg, const float* __restrict__ wyg,
    const float* __restrict__ wzg, float* __restrict__ outg,
    const float* __restrict__ gGt) {

    // LDS pool (floats), 7776 = 31104 B (5 blocks/CU):
    //  sXc [0,    2304)  xc/yc [side*9+d][c]       (B writes, C reads)
    //  sG  [2304, 4572)  Gaunt table               (A writes, C reads)
    //  sXY [4572, 6876)  x,y transposed [side][d*128+m]  (A/B)
    //  sZ  [4572, 7772)  z [dz][c]  -- aliases sXY (dead after B)
    __shared__ __align__(16) float pool[7776];
    float* sXc = pool;
    float* sG  = pool + 2304;
    float* sXY = pool + 4572;
    float* sZ  = pool + 4572;

    const int tid  = threadIdx.x;
    const int nb   = blockIdx.x;                    // node index
    const int lane = tid & 63;
    const int wave = __builtin_amdgcn_readfirstlane(tid >> 6);
    const float s128 = 0.08838834764831845f;        // 1/sqrt(128)

    // Stage A: x,y for node nb -> transposed sXY; Gaunt table -> sG
    {
        const float4* xs = (const float4*)(xg + (size_t)nb * 1152);
        const float4* ys = (const float4*)(yg + (size_t)nb * 1152);
        for (int i = tid; i < 576; i += 128) {
            float4 v = (i < 288) ? xs[i] : ys[i - 288];
            int r = (i < 288) ? i : i - 288;
            int base = (i < 288) ? 0 : 1152;
            int j0 = r * 4;
            #pragma unroll
            for (int k = 0; k < 4; ++k) {
                int j = j0 + k;                      // j = m*9 + d
                int m = j / 9, d = j - 9 * m;
                float val = (k == 0) ? v.x : (k == 1) ? v.y : (k == 2) ? v.z : v.w;
                sXY[base + d * 128 + m] = val;
            }
        }
        for (int i = tid; i < 567; i += 128)
            ((float4*)sG)[i] = ((const float4*)gGt)[i];
    }
    __syncthreads();

    // Stage B: linear_in. wave = side; lane owns c-pair (2*lane, 2*lane+1).
    // 12 float2 w-loads + 9 b128 x-broadcasts + 72 fma per m-chunk (per-thread
    // counts identical to R0). Per-(c,d) m-order unchanged -> bit-exact.
    {
        const int side = wave;
        const int c2 = lane << 1;
        const float* wb = side ? wyg : wxg;
        const float* xb = sXY + side * 1152;        // [d*128+m]
        float acc[18];                               // [d][cpair]
        #pragma unroll
        for (int i = 0; i < 18; ++i) acc[i] = 0.f;
        for (int m0 = 0; m0 < MULT; m0 += 4) {
            float2 w0[4], w1[4], w2[4];
            #pragma unroll
            for (int k = 0; k < 4; ++k) {
                w0[k] = *(const float2*)(wb + (m0 + k) * 128 + c2);
                w1[k] = *(const float2*)(wb + 16384 + (m0 + k) * 128 + c2);
                w2[k] = *(const float2*)(wb + 32768 + (m0 + k) * 128 + c2);
            }
            #pragma unroll
            for (int d = 0; d < 9; ++d) {
                const float2* wl = (d == 0) ? w0 : (d < 4) ? w1 : w2;
                float4 xv = *(const float4*)(xb + d * 128 + m0);    // broadcast
                acc[d*2+0] = fmaf(xv.x, wl[0].x, acc[d*2+0]);
                acc[d*2+0] = fmaf(xv.y, wl[1].x, acc[d*2+0]);
                acc[d*2+0] = fmaf(xv.z, wl[2].x, acc[d*2+0]);
                acc[d*2+0] = fmaf(xv.w, wl[3].x, acc[d*2+0]);
                acc[d*2+1] = fmaf(xv.x, wl[0].y, acc[d*2+1]);
                acc[d*2+1] = fmaf(xv.y, wl[1].y, acc[d*2+1]);
                acc[d*2+1] = fmaf(xv.z, wl[2].y, acc[d*2+1]);
                acc[d*2+1] = fmaf(xv.w, wl[3].y, acc[d*2+1]);
            }
        }
        #pragma unroll
        for (int d = 0; d < 9; ++d) {
            float2 v = make_float2(acc[d*2+0] * s128, acc[d*2+1] * s128);
            *(float2*)(sXc + (side * 9 + d) * 128 + c2) = v;
        }
    }
    __syncthreads();

    // Stage C: SPARSE z = G : (xc o yc). thread = c, full dz range, 1 node;
    // 162 rule-allowed terms (R4-proven bit-exact order).
    {
        const int c = tid;
        float xr[9], yr[9];
        #pragma unroll
        for (int d = 0; d < 9; ++d) {
            xr[d] = sXc[d * 128 + c];
            yr[d] = sXc[(9 + d) * 128 + c];
        }
        float a[DZ];
        #pragma unroll
        for (int i = 0; i < DZ; ++i) a[i] = 0.f;
        c_d1<0>(sG, xr, yr, a);
        #pragma unroll
        for (int dz = 0; dz < DZ; ++dz)
            sZ[dz * 128 + c] = a[dz];
    }
    __syncthreads();

    // Stage D: linear_out. wave0 -> l0+l1+l2 (d0..8), wave1 -> l3+l4 (d9..24);
    // e-pair lanes, direct global stores, no final barrier.
    float* po = outg + (size_t)nb * (CH * DZ);
    if (wave == 0) d_tile<0, 9, 0, 3>(sZ, wzg, po, lane);
    else           d_tile<9, 16, 3, 2>(sZ, wzg, po, lane);
}

extern "C" void kernel_launch(void* const* d_in, const int* in_sizes, int n_in,
                              void* d_out, int out_size, void* d_ws, size_t ws_size,
                              hipStream_t stream) {
    static float h_gGt[81 * 28];   // zero-init pads
    static bool built = false;
    if (!built) { host_build_gaunt(h_gGt); built = true; }
    hipMemcpyAsync(d_ws, h_gGt, sizeof(h_gGt), hipMemcpyHostToDevice, stream);

    int N = in_sizes[0] / (MULT * DIN);

    hipLaunchKernelGGL(gaunt_fused, dim3(N), dim3(128), 0, stream,
                       (const float*)d_in[0], (const float*)d_in[1],
                       (const float*)d_in[2], (const float*)d_in[3],
                       (const float*)d_in[4], (float*)d_out, (const float*)d_ws);
}